// Round 10
// baseline (737.424 us; speedup 1.0000x reference)
//
#include <hip/hip_runtime.h>
#include <hip/hip_bf16.h>
#include <math.h>

#define LSEQ 2048
#define HD   512
#define NST  32
#define LC   128
#define NCHK 16   /* LSEQ/LC */
#define NCG  32   /* HD/16 channel groups */
#define HH   (HD * HD)

typedef __bf16 bf16;
typedef __bf16 bf16x8 __attribute__((ext_vector_type(8)));
typedef float  floatx4 __attribute__((ext_vector_type(4)));

__device__ __forceinline__ float wave_reduce_add(float v) {
#pragma unroll
    for (int m = 32; m; m >>= 1) v += __shfl_xor(v, m, 64);
    return v;
}

__device__ __forceinline__ float gelu_tanh(float x) {
    float z = 0.7978845608028654f * (x + 0.044715f * x * x * x);
    float e = __expf(2.f * z);
    float th = 1.f - 2.f / (e + 1.f);   // tanh(z), saturates cleanly at e=inf
    return 0.5f * x * (1.f + th);
}

__device__ __forceinline__ void make_ab(float lre, float lim, float step,
                                        float br0, float bi0,
                                        float& ar, float& ai, float& br, float& bi) {
    float s2 = 0.5f * step;
    float dr = 1.f - s2 * lre, di = -s2 * lim;      // 1 - (dt/2)Lam
    float inv = 1.f / (dr * dr + di * di);
    float blr = dr * inv, bli = -di * inv;          // BL = 1/(dr+i*di)
    float nr = 1.f + s2 * lre, ni = s2 * lim;       // 1 + (dt/2)Lam
    ar = blr * nr - bli * ni;
    ai = blr * ni + bli * nr;
    float tr = step * br0, ti = step * bi0;         // dt * B
    br = blr * tr - bli * ti;
    bi = blr * ti + bli * tr;
}

// ============ setup: prep coeffs (0..255) + weight cvt (256..767)
// ============        + encoder w/ layer-0 LN-stat atomics (768..4863)
__global__ __launch_bounds__(256) void setup_kernel(
    const float* __restrict__ x,   const float* __restrict__ ew,
    const float* __restrict__ eb,
    const float* __restrict__ lre, const float* __restrict__ lim,
    const float* __restrict__ bre, const float* __restrict__ bim,
    const float* __restrict__ cre, const float* __restrict__ cim,
    const float* __restrict__ ls,  const float* __restrict__ ow,
    const float* __restrict__ o2w,
    float* __restrict__ h, bf16* __restrict__ wb,
    float2* __restrict__ cA, float2* __restrict__ cB,
    float2* __restrict__ cC, float2* __restrict__ cAp,
    float* __restrict__ st0)
{
    int bid = blockIdx.x, tid = threadIdx.x;
    if (bid < 256) {
        int tg = bid * 256 + tid;                   // 65536 = 4*HD*NST
        int lay = tg >> 14, rem = tg & 16383;
        int ch = rem >> 5, n = rem & 31;
        float step = __expf(ls[lay * HD + ch]);
        float ar, ai, br, bi;
        make_ab(lre[tg], lim[tg], step, bre[tg], bim[tg], ar, ai, br, bi);
        float xr = ar, xi = ai;                     // Abar^LC (LC=128: 7 squarings)
#pragma unroll
        for (int q = 0; q < 7; ++q) { float tt = xr * xr - xi * xi; xi = 2.f * xr * xi; xr = tt; }
        int dst = (lay * NST + n) * HD + ch;
        cA[dst]  = make_float2(ar, ai);
        cB[dst]  = make_float2(br, bi);
        cC[dst]  = make_float2(2.f * cre[tg], 2.f * cim[tg]);
        cAp[dst] = make_float2(xr, xi);
    } else if (bid < 768) {
        int i = ((bid - 256) * 256 + tid) * 8;      // covers 4*HH floats
        float4 a = *(const float4*)(ow + i);
        float4 b = *(const float4*)(ow + i + 4);
        bf16x8 o;
        o[0]=(bf16)a.x; o[1]=(bf16)a.y; o[2]=(bf16)a.z; o[3]=(bf16)a.w;
        o[4]=(bf16)b.x; o[5]=(bf16)b.y; o[6]=(bf16)b.z; o[7]=(bf16)b.w;
        *(bf16x8*)(wb + i) = o;
        a = *(const float4*)(o2w + i);
        b = *(const float4*)(o2w + i + 4);
        o[0]=(bf16)a.x; o[1]=(bf16)a.y; o[2]=(bf16)a.z; o[3]=(bf16)a.w;
        o[4]=(bf16)b.x; o[5]=(bf16)b.y; o[6]=(bf16)b.z; o[7]=(bf16)b.w;
        *(bf16x8*)(wb + 4 * HH + i) = o;
    } else {
        int i = (bid - 768) * 256 + tid;            // 1048576 = L*HD
        int t = i >> 9, c = i & 511;
        float4 xv = *(const float4*)(x + t * 4);
        float4 wv = *(const float4*)(ew + c * 4);
        float acc = eb[c];
        acc = fmaf(xv.x, wv.x, acc); acc = fmaf(xv.y, wv.y, acc);
        acc = fmaf(xv.z, wv.z, acc); acc = fmaf(xv.w, wv.w, acc);
        h[i] = acc;
        float s1 = wave_reduce_add(acc);
        float s2 = wave_reduce_add(acc * acc);
        if ((tid & 63) == 0) {
            atomicAdd(&st0[t * 2],     s1);
            atomicAdd(&st0[t * 2 + 1], s2);
        }
    }
}

// ============ single-pass chunked scan with decoupled lookback =================
// 512 blocks via atomic ticket: cg = vt&31 (16 ch), c = vt>>5 (chunk of 128 t).
// thread = (chl = tid>>4, sub = tid&15), 2 states n = 2*sub, 2*sub+1.
__global__ __launch_bounds__(256) void scan_kernel(
    const float* __restrict__ h, const float* __restrict__ st,
    const float2* __restrict__ cA, const float2* __restrict__ cB,
    const float2* __restrict__ cC, const float2* __restrict__ cAp,
    const float* __restrict__ dd,
    const float* __restrict__ nw, const float* __restrict__ nb,
    bf16* __restrict__ g, float2* __restrict__ agg,
    int* __restrict__ flags, int* __restrict__ ticket, int lay)
{
    __shared__ float  tile[LC * 16];    // 8 KB
    __shared__ float2 sml[LC];
    __shared__ float  snw[16], snb[16];
    __shared__ int    vt_s;
    const int tid = threadIdx.x;
    if (tid == 0) vt_s = atomicAdd(&ticket[lay], 1);
    __syncthreads();
    const int vt = vt_s;
    const int cg = vt & 31, c = vt >> 5;
    const int ch0 = cg * 16, t0 = c * LC;
    const int chl = tid >> 4, sub = tid & 15;
    const int ch = ch0 + chl, n0 = sub * 2;
    int* lflags = flags + lay * NCG * NCHK + cg * NCHK;

    // stage tile + LN stats
#pragma unroll
    for (int r = 0; r < 8; ++r) {
        int idx = r * 256 + tid;
        tile[idx] = h[(size_t)(t0 + (idx >> 4)) * HD + ch0 + (idx & 15)];
    }
    if (tid < LC) {
        float s1 = st[(t0 + tid) * 2], s2 = st[(t0 + tid) * 2 + 1];
        float m = s1 * (1.f / HD);
        float var = s2 * (1.f / HD) - m * m;
        sml[tid] = make_float2(m, rsqrtf(var + 1e-5f));
    }
    if (tid < 16) {
        snw[tid] = nw[lay * HD + ch0 + tid];
        snb[tid] = nb[lay * HD + ch0 + tid];
    }
    // coeffs (2 states)
    float aR[2], aI[2], bR[2], bI[2], cR[2], cI[2], apR[2], apI[2];
#pragma unroll
    for (int j = 0; j < 2; ++j) {
        int ci = (lay * NST + n0 + j) * HD + ch;
        float2 t = cA[ci];  aR[j] = t.x;  aI[j] = t.y;
        t = cB[ci];         bR[j] = t.x;  bI[j] = t.y;
        t = cC[ci];         cR[j] = t.x;  cI[j] = t.y;
        t = cAp[ci];        apR[j] = t.x; apI[j] = t.y;
    }
    float dch = dd[lay * HD + ch];
    __syncthreads();
    const float wch = snw[chl], bch = snb[chl];

    // ---- local chunk scan (zero init) ----
    float sr[2] = {0.f, 0.f}, si[2] = {0.f, 0.f};
#pragma unroll 4
    for (int t = 0; t < LC; ++t) {
        float2 ms = sml[t];
        float uu = (tile[t * 16 + chl] - ms.x) * ms.y * wch + bch;
#pragma unroll
        for (int j = 0; j < 2; ++j) {
            float nr = fmaf(aR[j], sr[j], fmaf(-aI[j], si[j], bR[j] * uu));
            float ni = fmaf(aI[j], sr[j], fmaf( aR[j], si[j], bI[j] * uu));
            sr[j] = nr; si[j] = ni;
        }
    }
    // ---- publish aggregate ----
    {
        size_t a = ((size_t)(cg * NCHK + c) * 512) + chl * 32 + n0;
        agg[a]     = make_float2(sr[0], si[0]);
        agg[a + 1] = make_float2(sr[1], si[1]);
    }
    __threadfence();
    __syncthreads();
    if (tid == 0) atomicExch(&lflags[c], 1);

    // ---- lookback: S = inclusive prefix through chunk c-1 (Horner ascending) ----
    float Sr[2] = {0.f, 0.f}, Si[2] = {0.f, 0.f};
    if (c > 0) {
        if (tid < c) {
            while (atomicAdd(&lflags[tid], 0) == 0) __builtin_amdgcn_s_sleep(2);
        }
        __syncthreads();
        __threadfence();
        float2 B0[8], B1[8];
#pragma unroll
        for (int i = 0; i < 8; ++i) if (i < c) {
            size_t a = ((size_t)(cg * NCHK + i) * 512) + chl * 32 + n0;
            B0[i] = agg[a]; B1[i] = agg[a + 1];
        }
#pragma unroll
        for (int i = 0; i < 8; ++i) if (i < c) {
            float nr = fmaf(apR[0], Sr[0], fmaf(-apI[0], Si[0], B0[i].x));
            float ni = fmaf(apI[0], Sr[0], fmaf( apR[0], Si[0], B0[i].y));
            Sr[0] = nr; Si[0] = ni;
            nr = fmaf(apR[1], Sr[1], fmaf(-apI[1], Si[1], B1[i].x));
            ni = fmaf(apI[1], Sr[1], fmaf( apR[1], Si[1], B1[i].y));
            Sr[1] = nr; Si[1] = ni;
        }
#pragma unroll
        for (int i = 8; i < 15; ++i) if (i < c) {
            size_t a = ((size_t)(cg * NCHK + i) * 512) + chl * 32 + n0;
            B0[i - 8] = agg[a]; B1[i - 8] = agg[a + 1];
        }
#pragma unroll
        for (int i = 8; i < 15; ++i) if (i < c) {
            float nr = fmaf(apR[0], Sr[0], fmaf(-apI[0], Si[0], B0[i - 8].x));
            float ni = fmaf(apI[0], Sr[0], fmaf( apR[0], Si[0], B0[i - 8].y));
            Sr[0] = nr; Si[0] = ni;
            nr = fmaf(apR[1], Sr[1], fmaf(-apI[1], Si[1], B1[i - 8].x));
            ni = fmaf(apI[1], Sr[1], fmaf( apR[1], Si[1], B1[i - 8].y));
            Sr[1] = nr; Si[1] = ni;
        }
    }

    // ---- replay with carry, emit gelu(y) as bf16 ----
    sr[0] = Sr[0]; si[0] = Si[0]; sr[1] = Sr[1]; si[1] = Si[1];
    bf16* gp = g + (size_t)t0 * HD + ch;
#pragma unroll 4
    for (int t = 0; t < LC; ++t) {
        float2 ms = sml[t];
        float uu = (tile[t * 16 + chl] - ms.x) * ms.y * wch + bch;
        float p0 = 0.f, p1 = 0.f;
#pragma unroll
        for (int j = 0; j < 2; ++j) {
            float nr = fmaf(aR[j], sr[j], fmaf(-aI[j], si[j], bR[j] * uu));
            float ni = fmaf(aI[j], sr[j], fmaf( aR[j], si[j], bI[j] * uu));
            sr[j] = nr; si[j] = ni;
            p0 = fmaf(cR[j], nr, p0);
            p1 = fmaf(-cI[j], ni, p1);
        }
        float p = p0 + p1;
        p += __shfl_xor(p, 1);
        p += __shfl_xor(p, 2);
        p += __shfl_xor(p, 4);
        p += __shfl_xor(p, 8);
        if (sub == 0) gp[(size_t)t * HD] = (bf16)gelu_tanh(fmaf(dch, uu, p));
    }
}

// ============ mm: gated dual-matmul + residual + NEXT layer's LN-stat atomics ==
__global__ __launch_bounds__(256) void mm_kernel(
    const bf16* __restrict__ A,
    const bf16* __restrict__ W1,
    const bf16* __restrict__ W2,
    const float* __restrict__ bias1, const float* __restrict__ bias2,
    float* __restrict__ Hio, float* __restrict__ stn) {
    const int w = threadIdx.x >> 6, lane = threadIdx.x & 63;
    const int wm = w >> 1, wn = w & 1;
    const int mBase = blockIdx.y * 64 + wm * 32;
    const int nBase = blockIdx.x * 64 + wn * 32;
    const int lrow = lane & 15, quad = lane >> 4;

    floatx4 acc1[2][2] = {{{0.f,0.f,0.f,0.f},{0.f,0.f,0.f,0.f}},{{0.f,0.f,0.f,0.f},{0.f,0.f,0.f,0.f}}};
    floatx4 acc2[2][2] = {{{0.f,0.f,0.f,0.f},{0.f,0.f,0.f,0.f}},{{0.f,0.f,0.f,0.f},{0.f,0.f,0.f,0.f}}};

    for (int k0 = 0; k0 < HD; k0 += 32) {
        int kk = k0 + quad * 8;
        bf16x8 a0 = *(const bf16x8*)(A + (mBase + lrow) * HD + kk);
        bf16x8 a1 = *(const bf16x8*)(A + (mBase + 16 + lrow) * HD + kk);
        bf16x8 p0 = *(const bf16x8*)(W1 + (nBase + lrow) * HD + kk);
        bf16x8 p1 = *(const bf16x8*)(W1 + (nBase + 16 + lrow) * HD + kk);
        bf16x8 q0 = *(const bf16x8*)(W2 + (nBase + lrow) * HD + kk);
        bf16x8 q1 = *(const bf16x8*)(W2 + (nBase + 16 + lrow) * HD + kk);
        acc1[0][0] = __builtin_amdgcn_mfma_f32_16x16x32_bf16(a0, p0, acc1[0][0], 0, 0, 0);
        acc1[0][1] = __builtin_amdgcn_mfma_f32_16x16x32_bf16(a0, p1, acc1[0][1], 0, 0, 0);
        acc1[1][0] = __builtin_amdgcn_mfma_f32_16x16x32_bf16(a1, p0, acc1[1][0], 0, 0, 0);
        acc1[1][1] = __builtin_amdgcn_mfma_f32_16x16x32_bf16(a1, p1, acc1[1][1], 0, 0, 0);
        acc2[0][0] = __builtin_amdgcn_mfma_f32_16x16x32_bf16(a0, q0, acc2[0][0], 0, 0, 0);
        acc2[0][1] = __builtin_amdgcn_mfma_f32_16x16x32_bf16(a0, q1, acc2[0][1], 0, 0, 0);
        acc2[1][0] = __builtin_amdgcn_mfma_f32_16x16x32_bf16(a1, q0, acc2[1][0], 0, 0, 0);
        acc2[1][1] = __builtin_amdgcn_mfma_f32_16x16x32_bf16(a1, q1, acc2[1][1], 0, 0, 0);
    }

    float hv[2][2][4];
#pragma unroll
    for (int fm = 0; fm < 2; ++fm)
#pragma unroll
        for (int fn = 0; fn < 2; ++fn) {
            int j = nBase + fn * 16 + lrow;
            float bb1 = bias1[j], bb2 = bias2[j];
#pragma unroll
            for (int r = 0; r < 4; ++r) {
                int t = mBase + fm * 16 + quad * 4 + r;
                float z1 = acc1[fm][fn][r] + bb1;
                float z2 = acc2[fm][fn][r] + bb2;
                float nv = Hio[t * HD + j] + z1 / (1.f + __expf(-z2));
                Hio[t * HD + j] = nv;
                hv[fm][fn][r] = nv;
            }
        }
#pragma unroll
    for (int fm = 0; fm < 2; ++fm)
#pragma unroll
        for (int r = 0; r < 4; ++r) {
            int t = mBase + fm * 16 + quad * 4 + r;
            float s1 = hv[fm][0][r] + hv[fm][1][r];
            float s2 = hv[fm][0][r] * hv[fm][0][r] + hv[fm][1][r] * hv[fm][1][r];
#pragma unroll
            for (int m = 1; m < 16; m <<= 1) {
                s1 += __shfl_xor(s1, m);
                s2 += __shfl_xor(s2, m);
            }
            if (lrow == 0) {
                atomicAdd(&stn[t * 2],     s1);
                atomicAdd(&stn[t * 2 + 1], s2);
            }
        }
}

// ============ decoder ============
__global__ __launch_bounds__(192) void dec_kernel(
    const float* __restrict__ h, const float* __restrict__ w,
    const float* __restrict__ b, float* __restrict__ out) {
    int j = threadIdx.x >> 6, lane = threadIdx.x & 63;
    int t = blockIdx.x;
    const float* hp = h + t * HD + lane * 8;
    float v[8];
    *(float4*)(v)     = *(const float4*)(hp);
    *(float4*)(v + 4) = *(const float4*)(hp + 4);
    float w8[8];
    *(float4*)(w8)     = *(const float4*)(w + j * HD + lane * 8);
    *(float4*)(w8 + 4) = *(const float4*)(w + j * HD + lane * 8 + 4);
    float s = 0.f;
#pragma unroll
    for (int e = 0; e < 8; ++e) s = fmaf(v[e], w8[e], s);
    s = wave_reduce_add(s);
    if (lane == 0) out[t * 3 + j] = s + b[j];
}

extern "C" void kernel_launch(void* const* d_in, const int* in_sizes, int n_in,
                              void* d_out, int out_size, void* d_ws, size_t ws_size,
                              hipStream_t stream) {
    const float* x   = (const float*)d_in[0];
    const float* ew  = (const float*)d_in[1];
    const float* eb  = (const float*)d_in[2];
    const float* dw  = (const float*)d_in[3];
    const float* db  = (const float*)d_in[4];
    const float* nw  = (const float*)d_in[5];
    const float* nb  = (const float*)d_in[6];
    const float* lre = (const float*)d_in[7];
    const float* lim = (const float*)d_in[8];
    const float* bre = (const float*)d_in[9];
    const float* bim = (const float*)d_in[10];
    const float* cre = (const float*)d_in[11];
    const float* cim = (const float*)d_in[12];
    const float* dd  = (const float*)d_in[13];
    const float* ls  = (const float*)d_in[14];
    const float* ow  = (const float*)d_in[15];
    const float* ob  = (const float*)d_in[16];
    const float* o2w = (const float*)d_in[17];
    const float* o2b = (const float*)d_in[18];
    char* ws = (char*)d_ws;

    float*  h      = (float*)ws;                            // 4 MB [L][HD]
    float2* agg    = (float2*)(ws + (4 << 20));             // 2 MB [cg][c][512]
    bf16*   g      = (bf16*)(ws + (6 << 20));               // 2 MB [L][HD]
    bf16*   wb     = (bf16*)(ws + (8 << 20));               // 4 MB bf16 weights
    float*  stats  = (float*)(ws + (12 << 20));             // 80 KB
    int*    flags  = (int*)(ws + (12 << 20) + (256 << 10)); // 8 KB
    int*    ticket = (int*)(ws + (12 << 20) + (384 << 10)); // 16 B
    float2* cA     = (float2*)(ws + (13 << 20));            // 4 x 512 KB
    float2* cB     = cA + 4 * NST * HD;
    float2* cC     = cB + 4 * NST * HD;
    float2* cAp    = cC + 4 * NST * HD;

    hipMemsetAsync(ws + (12 << 20), 0, 512 << 10, stream);  // stats + flags + tickets
    setup_kernel<<<4864, 256, 0, stream>>>(x, ew, eb, lre, lim, bre, bim,
                                           cre, cim, ls, ow, o2w,
                                           h, wb, cA, cB, cC, cAp, stats);
    for (int lay = 0; lay < 4; ++lay) {
        float* st  = stats + lay * LSEQ * 2;
        float* stn = stats + (lay + 1) * LSEQ * 2;
        scan_kernel<<<NCG * NCHK, 256, 0, stream>>>(
            h, st, cA, cB, cC, cAp, dd, nw, nb, g, agg, flags, ticket, lay);
        mm_kernel<<<dim3(8, 32), 256, 0, stream>>>(
            g, wb + lay * HH, wb + 4 * HH + lay * HH,
            ob + lay * HD, o2b + lay * HD, h, stn);
    }
    dec_kernel<<<LSEQ, 192, 0, stream>>>(h, dw, db, (float*)d_out);
}